// Round 2
// baseline (388.600 us; speedup 1.0000x reference)
//
#include <hip/hip_runtime.h>
#include <hip/hip_bf16.h>
#include <stdint.h>

typedef __bf16 bf16x8 __attribute__((ext_vector_type(8)));
typedef float  f32x4  __attribute__((ext_vector_type(4)));

#define MFMA16(a, b, c) __builtin_amdgcn_mfma_f32_16x16x32_bf16(a, b, c, 0, 0, 0)

// async 16B global->LDS (dest = wave-uniform base + lane*16)
__device__ __forceinline__ void ld16(void* lds, const void* g) {
    __builtin_amdgcn_global_load_lds(
        (const __attribute__((address_space(1))) void*)(uintptr_t)g,
        (__attribute__((address_space(3))) void*)(uint32_t)(uintptr_t)lds,
        16, 0, 0);
}

// ---------------- f32 -> bf16 convert (x) -------------------------------------
__global__ __launch_bounds__(256) void convert_bf16(const float* __restrict__ src,
                                                    __bf16* __restrict__ dst) {
    int i = (blockIdx.x * 256 + threadIdx.x) * 4;
    float4 v = *(const float4*)(src + i);
    dst[i]     = (__bf16)v.x;
    dst[i + 1] = (__bf16)v.y;
    dst[i + 2] = (__bf16)v.z;
    dst[i + 3] = (__bf16)v.w;
}

// ---------------- weight transpose + cast: Wt[n][k] = (bf16)W[k][n] -----------
__global__ __launch_bounds__(1024) void transpose_w(const float* __restrict__ W0,
                                                    const float* __restrict__ W1,
                                                    const float* __restrict__ W2,
                                                    const float* __restrict__ W3,
                                                    __bf16* __restrict__ dst) {
    __shared__ __bf16 t[32][33];
    const int z = blockIdx.z;
    const float* W = (z == 0) ? W0 : (z == 1) ? W1 : (z == 2) ? W2 : W3;
    __bf16* D = dst + (size_t)z * 1048576;
    const int tx = threadIdx.x, ty = threadIdx.y;
    t[ty][tx] = (__bf16)W[(size_t)(blockIdx.y * 32 + ty) * 1024 + blockIdx.x * 32 + tx];
    __syncthreads();
    D[(size_t)(blockIdx.x * 32 + ty) * 1024 + blockIdx.y * 32 + tx] = t[tx][ty];
}

// ---------------- shared GEMM mainloop: C[128x128] += A[128xK] * BT[128xK]^T ----
// A row-major [M,K] bf16; BT row-major [N,K] bf16. m97 structure.
__device__ __forceinline__ void gemm_mainloop(const __bf16* __restrict__ A,
                                              const __bf16* __restrict__ BT,
                                              int K, __bf16* As, __bf16* Bs,
                                              f32x4 acc[4][4]) {
    const int tid  = threadIdx.x;
    const int lane = tid & 63;
    const int wid  = tid >> 6;
    const int quad = lane >> 4;
    const int l16  = lane & 15;
    const int wm   = wid >> 1;
    const int wn   = wid & 1;

    const int srow = wid * 16 + (lane >> 2);   // staging row 0..63
    const int scol = (lane & 3) * 8;           // k-chunk within 32
    const int sdst = wid * 512 + lane * 8;     // LDS elem offset (=lane*16B per wave)

    for (int k0 = 0; k0 < K; k0 += 32) {
        ld16(As + sdst,        A  + (size_t)srow        * K + k0 + scol);
        ld16(As + 2048 + sdst, A  + (size_t)(srow + 64) * K + k0 + scol);
        ld16(Bs + sdst,        BT + (size_t)srow        * K + k0 + scol);
        ld16(Bs + 2048 + sdst, BT + (size_t)(srow + 64) * K + k0 + scol);
        __syncthreads();
        bf16x8 af[4], bf[4];
#pragma unroll
        for (int mt = 0; mt < 4; mt++)
            af[mt] = *(const bf16x8*)(As + (wm * 64 + mt * 16 + l16) * 32 + quad * 8);
#pragma unroll
        for (int nt = 0; nt < 4; nt++)
            bf[nt] = *(const bf16x8*)(Bs + (wn * 64 + nt * 16 + l16) * 32 + quad * 8);
#pragma unroll
        for (int mt = 0; mt < 4; mt++)
#pragma unroll
            for (int nt = 0; nt < 4; nt++)
                acc[mt][nt] = MFMA16(af[mt], bf[nt], acc[mt][nt]);
        __syncthreads();
    }
}

// ---------------- V transpose per head: [B,H,T,HD] -> [B,H,HD,T] (bf16) --------
__global__ __launch_bounds__(1024) void transpose_v(const __bf16* __restrict__ V,
                                                    __bf16* __restrict__ Vt) {
    __shared__ __bf16 t[32][33];
    const int bh = blockIdx.z;
    const int t0 = blockIdx.x * 32;
    const int d0 = blockIdx.y * 32;
    const int tx = threadIdx.x, ty = threadIdx.y;
    t[ty][tx] = V[((size_t)bh * 2048 + t0 + ty) * 64 + d0 + tx];
    __syncthreads();
    Vt[((size_t)bh * 64 + d0 + ty) * 2048 + t0 + tx] = t[tx][ty];
}

// ---------------- QKV projection: X @ W{q,k,v} + b -> [B,H,T,HD] bf16 ----------
__global__ __launch_bounds__(256) void qkv_gemm(const __bf16* __restrict__ X,
                                                const __bf16* __restrict__ WTb,
                                                const float* __restrict__ b0,
                                                const float* __restrict__ b1,
                                                const float* __restrict__ b2,
                                                __bf16* __restrict__ qkv) {
    __shared__ __attribute__((aligned(16))) __bf16 As[4096];
    __shared__ __attribute__((aligned(16))) __bf16 Bs[4096];
    const int z = blockIdx.z;
    const __bf16* BT   = WTb + (size_t)z * 1048576;
    const float* bias  = (z == 0) ? b0 : (z == 1) ? b1 : b2;
    __bf16* dst = qkv + (size_t)z * 4194304;
    const int m0 = blockIdx.y * 128, n0 = blockIdx.x * 128;
    f32x4 acc[4][4];
    const f32x4 zz = {0.f, 0.f, 0.f, 0.f};
#pragma unroll
    for (int i = 0; i < 4; i++)
#pragma unroll
        for (int j = 0; j < 4; j++) acc[i][j] = zz;
    gemm_mainloop(X + (size_t)m0 * 1024, BT + (size_t)n0 * 1024, 1024, As, Bs, acc);

    const int lane = threadIdx.x & 63, wid = threadIdx.x >> 6;
    const int quad = lane >> 4, l16 = lane & 15, wm = wid >> 1, wn = wid & 1;
#pragma unroll
    for (int nt = 0; nt < 4; nt++) {
        int col = n0 + wn * 64 + nt * 16 + l16;
        float bv = bias[col];
        int h = col >> 6, hd = col & 63;
#pragma unroll
        for (int mt = 0; mt < 4; mt++) {
#pragma unroll
            for (int r4 = 0; r4 < 4; r4++) {
                int m = m0 + wm * 64 + mt * 16 + quad * 4 + r4;
                int b = m >> 11, tt = m & 2047;
                float v = acc[mt][nt][r4] + bv;
                dst[((size_t)((b * 16 + h) * 2048 + tt)) * 64 + hd] = (__bf16)v;
            }
        }
    }
}

// ---------------- output projection: Y @ Wp + bp -> out [B,T,C] f32 ------------
__global__ __launch_bounds__(256) void proj_gemm(const __bf16* __restrict__ Yw,
                                                 const __bf16* __restrict__ WT,
                                                 const float* __restrict__ bias,
                                                 float* __restrict__ out) {
    __shared__ __attribute__((aligned(16))) __bf16 As[4096];
    __shared__ __attribute__((aligned(16))) __bf16 Bs[4096];
    const int m0 = blockIdx.y * 128, n0 = blockIdx.x * 128;
    f32x4 acc[4][4];
    const f32x4 zz = {0.f, 0.f, 0.f, 0.f};
#pragma unroll
    for (int i = 0; i < 4; i++)
#pragma unroll
        for (int j = 0; j < 4; j++) acc[i][j] = zz;
    gemm_mainloop(Yw + (size_t)m0 * 1024, WT + (size_t)n0 * 1024, 1024, As, Bs, acc);

    const int lane = threadIdx.x & 63, wid = threadIdx.x >> 6;
    const int quad = lane >> 4, l16 = lane & 15, wm = wid >> 1, wn = wid & 1;
#pragma unroll
    for (int nt = 0; nt < 4; nt++) {
        int col = n0 + wn * 64 + nt * 16 + l16;
        float bv = bias[col];
#pragma unroll
        for (int mt = 0; mt < 4; mt++) {
#pragma unroll
            for (int r4 = 0; r4 < 4; r4++) {
                int m = m0 + wm * 64 + mt * 16 + quad * 4 + r4;
                out[(size_t)m * 1024 + col] = acc[mt][nt][r4] + bv;
            }
        }
    }
}

// ---------------- flash attention: one (b,h) x 128-q-tile per block -------------
__global__ __launch_bounds__(256) void attn_kernel(const __bf16* __restrict__ Qg,
                                                   const __bf16* __restrict__ Kg,
                                                   const __bf16* __restrict__ Vtg,
                                                   __bf16* __restrict__ Y) {
    __shared__ __attribute__((aligned(16))) __bf16 Qs[128 * 64];
    __shared__ __attribute__((aligned(16))) __bf16 Ks[128 * 64];
    __shared__ __attribute__((aligned(16))) __bf16 Vs[64 * 128];
    __shared__ __attribute__((aligned(16))) __bf16 Ps[128 * 136];
    __shared__ float Sf[128 * 132];
    __shared__ float mrow[128], lrow[128], arow[128];

    const int tid = threadIdx.x;
    const int lane = tid & 63;
    const int wid  = tid >> 6;
    const int quad = lane >> 4;
    const int l16  = lane & 15;
    const int wm = wid >> 1, wn = wid & 1;
    const int bx = blockIdx.x, bh = blockIdx.y;
    const int q0 = bx * 128;
    const size_t hbase = (size_t)bh * (2048 * 64);

    // stage Q tile (chunk-swizzled: LDS chunk c holds global chunk c ^ (row&7))
    {
        const int c = lane & 7;
#pragma unroll
        for (int r = 0; r < 4; r++) {
            int rr = r * 32 + wid * 8 + (lane >> 3);
            int gc = c ^ (rr & 7);
            ld16(Qs + rr * 64 + c * 8, Qg + hbase + (size_t)(q0 + rr) * 64 + gc * 8);
        }
    }
    if (tid < 128) { mrow[tid] = -1e38f; lrow[tid] = 0.f; }

    f32x4 acc_o[2][4];
    const f32x4 zz = {0.f, 0.f, 0.f, 0.f};
#pragma unroll
    for (int i = 0; i < 2; i++)
#pragma unroll
        for (int j = 0; j < 4; j++) acc_o[i][j] = zz;

    for (int kt = 0; kt <= bx; kt++) {
        const int key0 = kt * 128;
        {   // stage K tile
            const int c = lane & 7;
#pragma unroll
            for (int r = 0; r < 4; r++) {
                int rr = r * 32 + wid * 8 + (lane >> 3);
                int gc = c ^ (rr & 7);
                ld16(Ks + rr * 64 + c * 8, Kg + hbase + (size_t)(key0 + rr) * 64 + gc * 8);
            }
        }
        {   // stage V^T tile [64 hd][128 key] (chunk-swizzled by hd&15)
            const int c = lane & 15;
#pragma unroll
            for (int r = 0; r < 4; r++) {
                int hd = r * 16 + wid * 4 + (lane >> 4);
                int gc = c ^ (hd & 15);
                ld16(Vs + hd * 128 + c * 8,
                     Vtg + ((size_t)bh * 64 + hd) * 2048 + key0 + gc * 8);
            }
        }
        __syncthreads();

        // S = Q K^T (this wave's 64x64 quadrant)
        f32x4 accs[4][4];
#pragma unroll
        for (int i = 0; i < 4; i++)
#pragma unroll
            for (int j = 0; j < 4; j++) accs[i][j] = zz;
#pragma unroll
        for (int kk = 0; kk < 2; kk++) {
            bf16x8 qf[4], kf[4];
#pragma unroll
            for (int mt = 0; mt < 4; mt++) {
                int row = wm * 64 + mt * 16 + l16;
                int cg = kk * 4 + quad;
                qf[mt] = *(const bf16x8*)(Qs + row * 64 + ((cg ^ (row & 7)) * 8));
            }
#pragma unroll
            for (int nt = 0; nt < 4; nt++) {
                int row = wn * 64 + nt * 16 + l16;
                int cg = kk * 4 + quad;
                kf[nt] = *(const bf16x8*)(Ks + row * 64 + ((cg ^ (row & 7)) * 8));
            }
#pragma unroll
            for (int mt = 0; mt < 4; mt++)
#pragma unroll
                for (int nt = 0; nt < 4; nt++)
                    accs[mt][nt] = MFMA16(qf[mt], kf[nt], accs[mt][nt]);
        }
        // scaled + causal-masked scores -> LDS (f32)
#pragma unroll
        for (int mt = 0; mt < 4; mt++)
#pragma unroll
            for (int nt = 0; nt < 4; nt++) {
                int col = wn * 64 + nt * 16 + l16;
#pragma unroll
                for (int r4 = 0; r4 < 4; r4++) {
                    int row = wm * 64 + mt * 16 + quad * 4 + r4;
                    float v = accs[mt][nt][r4] * 0.125f;
                    if (key0 + col > q0 + row) v = -1e30f;
                    Sf[row * 132 + col] = v;
                }
            }
        __syncthreads();

        // online softmax: 2 threads per q-row
        {
            int row = tid >> 1;
            int base = row * 132 + (tid & 1) * 64;
            int pbase = row * 136 + (tid & 1) * 64;
            float mx = -1e38f;
#pragma unroll 8
            for (int j = 0; j < 64; j++) mx = fmaxf(mx, Sf[base + j]);
            mx = fmaxf(mx, __shfl_xor(mx, 1));
            float mprev = mrow[row];
            float mnew = fmaxf(mprev, mx);
            float s = 0.f;
#pragma unroll 8
            for (int j = 0; j < 64; j++) {
                float e = __expf(Sf[base + j] - mnew);
                Ps[pbase + j] = (__bf16)e;
                s += e;
            }
            s += __shfl_xor(s, 1);
            if ((tid & 1) == 0) {
                float al = __expf(mprev - mnew);
                lrow[row] = lrow[row] * al + s;
                arow[row] = al;
                mrow[row] = mnew;
            }
        }
        __syncthreads();

        // rescale O, then O += P @ V (wave handles q-rows [wid*32, wid*32+32))
#pragma unroll
        for (int mt = 0; mt < 2; mt++)
#pragma unroll
            for (int r4 = 0; r4 < 4; r4++) {
                float al = arow[wid * 32 + mt * 16 + quad * 4 + r4];
#pragma unroll
                for (int nt = 0; nt < 4; nt++) acc_o[mt][nt][r4] *= al;
            }
#pragma unroll
        for (int kk = 0; kk < 4; kk++) {
            bf16x8 pf[2], vf[4];
#pragma unroll
            for (int mt = 0; mt < 2; mt++) {
                int row = wid * 32 + mt * 16 + l16;
                pf[mt] = *(const bf16x8*)(Ps + row * 136 + kk * 32 + quad * 8);
            }
#pragma unroll
            for (int nt = 0; nt < 4; nt++) {
                int hd = nt * 16 + l16;
                int cg = kk * 4 + quad;
                vf[nt] = *(const bf16x8*)(Vs + hd * 128 + ((cg ^ (hd & 15)) * 8));
            }
#pragma unroll
            for (int mt = 0; mt < 2; mt++)
#pragma unroll
                for (int nt = 0; nt < 4; nt++)
                    acc_o[mt][nt] = MFMA16(pf[mt], vf[nt], acc_o[mt][nt]);
        }
        __syncthreads();
    }

    // epilogue: Y[b, q, h*64+hd] = O / l
    const int b = bh >> 4, h = bh & 15;
#pragma unroll
    for (int mt = 0; mt < 2; mt++)
#pragma unroll
        for (int r4 = 0; r4 < 4; r4++) {
            int row = wid * 32 + mt * 16 + quad * 4 + r4;
            float inv = 1.f / lrow[row];
#pragma unroll
            for (int nt = 0; nt < 4; nt++) {
                int col = h * 64 + nt * 16 + l16;
                Y[((size_t)(b * 2048 + q0 + row)) * 1024 + col] =
                    (__bf16)(acc_o[mt][nt][r4] * inv);
            }
        }
}

// ws layout (bf16 elems), 40 MB total:
// [0,4Mi)       x as bf16  (dead after qkv_gemm)  -> reused as V^T
// [4Mi,8Mi)     W^T x4 (Wq,Wk,Wv,Wp)
// [8Mi,12Mi)    Q   [B,H,T,HD]
// [12Mi,16Mi)   K   [B,H,T,HD]
// [16Mi,20Mi)   V   [B,H,T,HD]  (dead after transpose_v) -> reused as Y [B,T,C]
#define XB_OFF  0
#define WT_OFF  4194304
#define Q_OFF   8388608
#define K_OFF   12582912
#define V_OFF   16777216
#define VT_OFF  0
#define Y_OFF   16777216

extern "C" void kernel_launch(void* const* d_in, const int* in_sizes, int n_in,
                              void* d_out, int out_size, void* d_ws, size_t ws_size,
                              hipStream_t stream) {
    const float* x  = (const float*)d_in[0];
    const float* Wq = (const float*)d_in[1];
    const float* bq = (const float*)d_in[2];
    const float* Wk = (const float*)d_in[3];
    const float* bk = (const float*)d_in[4];
    const float* Wv = (const float*)d_in[5];
    const float* bv = (const float*)d_in[6];
    const float* Wp = (const float*)d_in[7];
    const float* bp = (const float*)d_in[8];
    __bf16* ws  = (__bf16*)d_ws;
    float*  out = (float*)d_out;
    if (ws_size < (size_t)41943040) return;  // need 40 MB scratch

    convert_bf16<<<4096, 256, 0, stream>>>(x, ws + XB_OFF);
    transpose_w<<<dim3(32, 32, 4), dim3(32, 32), 0, stream>>>(Wq, Wk, Wv, Wp, ws + WT_OFF);
    qkv_gemm<<<dim3(8, 32, 3), 256, 0, stream>>>(ws + XB_OFF, ws + WT_OFF, bq, bk, bv, ws + Q_OFF);
    transpose_v<<<dim3(64, 2, 32), dim3(32, 32), 0, stream>>>(ws + V_OFF, ws + VT_OFF);
    attn_kernel<<<dim3(16, 32), 256, 0, stream>>>(ws + Q_OFF, ws + K_OFF, ws + VT_OFF, ws + Y_OFF);
    proj_gemm<<<dim3(8, 32), 256, 0, stream>>>(ws + Y_OFF, ws + WT_OFF + 3 * 1048576, bp, out);
}